// Round 5
// baseline (185.746 us; speedup 1.0000x reference)
//
#include <hip/hip_runtime.h>
#include <hip/hip_fp16.h>

// out[b, i*16+k, 2m(+1), 2n(+1)] = x + sum_j (sum_g rd_g * Up(sigmoid(depth))[g,i,j,k]) * x_j
// Up = 2x bilinear (half-pixel, edge-clamped); rd[g] = max(1 - |g - depth_ori*3|, 0)
//
// Decomposition: one wave = (b, oc, m-tile of 8 input rows), lane == input col n.
// Rolling sigmoid rows sA/sB/sC: each depth row loaded+sigmoided ONCE (was 3x).
// Horizontal taps via packed-f16 shuffles (__shfl edge clamp == column clamp).
// 1024 blocks = 4 blocks/CU -> entire grid co-resident in one generation.

__device__ __forceinline__ float sigmoid_fast(float v) {
    float e = __builtin_amdgcn_exp2f(v * -1.44269504088896340736f);
    return __builtin_amdgcn_rcpf(1.0f + e);
}

#define NCH 12  // 3 g * 4 j channels per (b, oc)

__global__ __launch_bounds__(256, 4) void seblock_kernel(
    const float* __restrict__ x,
    const float* __restrict__ depth,
    const float* __restrict__ dori,
    float* __restrict__ out)
{
    const int lane = threadIdx.x & 63;                                  // input col n
    const int wsub = __builtin_amdgcn_readfirstlane(threadIdx.x >> 6);  // SGPR
    const int wid  = (blockIdx.x << 2) | wsub;
    const int mt = wid & 7;          // m-tile
    const int oc = (wid >> 3) & 63;
    const int b  = wid >> 9;
    const int i  = oc >> 4;
    const int k  = oc & 15;
    const int m0 = mt << 3;

    // scalar per-channel element offsets into depth (int: max ~25.2M)
    int cofs[NCH];
    #pragma unroll
    for (int g = 0; g < 3; ++g)
        #pragma unroll
        for (int j = 0; j < 4; ++j)
            cofs[g * 4 + j] = (b * 768 + g * 256 + i * 64 + j * 16 + k) * 4096;

    auto rowoff = [](int r) { return ((r < 0) ? 0 : (r > 63 ? 63 : r)) * 64; };

    // ---- prologue: rows m0-1, m0, m0+1 ----
    float rawA[NCH], rawB[NCH], raw[NCH];
    {
        const int rA = rowoff(m0 - 1), rB = rowoff(m0), rC = rowoff(m0 + 1);
        #pragma unroll
        for (int c = 0; c < NCH; ++c) rawA[c] = depth[cofs[c] + rA + lane];
        #pragma unroll
        for (int c = 0; c < NCH; ++c) rawB[c] = depth[cofs[c] + rB + lane];
        #pragma unroll
        for (int c = 0; c < NCH; ++c) raw[c]  = depth[cofs[c] + rC + lane];
    }

    float sA[NCH], sB[NCH], sC[NCH];
    #pragma unroll
    for (int c = 0; c < NCH; ++c) sA[c] = sigmoid_fast(rawA[c]);
    #pragma unroll
    for (int c = 0; c < NCH; ++c) sB[c] = sigmoid_fast(rawB[c]);

    const int xk   = (b * 64 + k) * 16384;   // + (j*16)*16384 + h0*128, scalar
    const int dob  = b * 16384;
    const int outb = (b * 64 + oc) * 16384;
    const int ln2  = 2 * lane;               // the only vector offset for x/dori/out

    const __half2 c25 = __float2half2_rn(0.25f);
    const __half2 c75 = __float2half2_rn(0.75f);

    #pragma unroll
    for (int t = 0; t < 8; ++t) {
        const int m = m0 + t;
        const int h0off = (m << 1) * 128;    // scalar

        // x, dori for this m (issue early)
        float xs[4][4];
        #pragma unroll
        for (int j = 0; j < 4; ++j) {
            const float2 a  = *reinterpret_cast<const float2*>(x + xk + j * 262144 + h0off + ln2);
            const float2 c2 = *reinterpret_cast<const float2*>(x + xk + j * 262144 + h0off + 128 + ln2);
            xs[j][0] = a.x; xs[j][1] = a.y; xs[j][2] = c2.x; xs[j][3] = c2.y;
        }
        const float2 q0 = *reinterpret_cast<const float2*>(dori + dob + h0off + ln2);
        const float2 q1 = *reinterpret_cast<const float2*>(dori + dob + h0off + 128 + ln2);

        // sigmoid of row m+1 (loaded last iteration / prologue)
        #pragma unroll
        for (int c = 0; c < NCH; ++c) sC[c] = sigmoid_fast(raw[c]);

        // prefetch row m+2
        if (t < 7) {
            const int rN = rowoff(m + 2);
            #pragma unroll
            for (int c = 0; c < NCH; ++c) raw[c] = depth[cofs[c] + rN + lane];
        }

        const float z0 = q0.x * 3.0f, z1 = q0.y * 3.0f, z2 = q1.x * 3.0f, z3 = q1.y * 3.0f;

        float acc0 = xs[i][0], acc1 = xs[i][1], acc2 = xs[i][2], acc3 = xs[i][3];
        #pragma unroll
        for (int g = 0; g < 3; ++g) {
            float d0 = 0.0f, d1 = 0.0f, d2 = 0.0f, d3 = 0.0f;
            #pragma unroll
            for (int j = 0; j < 4; ++j) {
                const int c = g * 4 + j;
                // vt (out-row 2m)  = 0.25*s[m-1] + 0.75*s[m]   (low half)
                // vb (out-row 2m+1)= 0.25*s[m+1] + 0.75*s[m]   (high half)
                const __half2 a02 = __floats2half2_rn(sA[c], sC[c]);
                const __half2 a11 = __float2half2_rn(sB[c]);
                const __half2 vtb = __hfma2(a02, c25, __hmul2(a11, c75));
                const int vi = __builtin_bit_cast(int, vtb);
                const __half2 vm = __builtin_bit_cast(__half2, __shfl_up(vi, 1));
                const __half2 vp = __builtin_bit_cast(__half2, __shfl_down(vi, 1));
                const __half2 tt  = __hmul2(vtb, c75);
                const __half2 u02 = __hfma2(vm, c25, tt);   // col 2n:   rows (2m, 2m+1)
                const __half2 u13 = __hfma2(vp, c25, tt);   // col 2n+1: rows (2m, 2m+1)
                d0 = fmaf(__low2float(u02),  xs[j][0], d0);
                d1 = fmaf(__low2float(u13),  xs[j][1], d1);
                d2 = fmaf(__high2float(u02), xs[j][2], d2);
                d3 = fmaf(__high2float(u13), xs[j][3], d3);
            }
            const float gf = (float)g;
            acc0 = fmaf(fmaxf(1.0f - fabsf(gf - z0), 0.0f), d0, acc0);
            acc1 = fmaf(fmaxf(1.0f - fabsf(gf - z1), 0.0f), d1, acc1);
            acc2 = fmaf(fmaxf(1.0f - fabsf(gf - z2), 0.0f), d2, acc2);
            acc3 = fmaf(fmaxf(1.0f - fabsf(gf - z3), 0.0f), d3, acc3);
        }

        *reinterpret_cast<float2*>(out + outb + h0off + ln2)       = make_float2(acc0, acc1);
        *reinterpret_cast<float2*>(out + outb + h0off + 128 + ln2) = make_float2(acc2, acc3);

        // rotate rolling rows (full unroll -> pure register renaming)
        #pragma unroll
        for (int c = 0; c < NCH; ++c) { sA[c] = sB[c]; sB[c] = sC[c]; }
    }
}

extern "C" void kernel_launch(void* const* d_in, const int* in_sizes, int n_in,
                              void* d_out, int out_size, void* d_ws, size_t ws_size,
                              hipStream_t stream) {
    const float* x     = (const float*)d_in[0];
    const float* depth = (const float*)d_in[1];
    const float* dori  = (const float*)d_in[2];
    float* out = (float*)d_out;

    // waves: b(8) * oc(64) * mt(8) = 4096 -> 1024 blocks of 256 (4 blocks/CU, all resident)
    seblock_kernel<<<1024, 256, 0, stream>>>(x, depth, dori, out);
}